// Round 9
// baseline (353.904 us; speedup 1.0000x reference)
//
#include <hip/hip_runtime.h>

// BrickVectorEdgeModel on MI355X (gfx950).
// R9: R8's coverage bug fixed. R8 split waves 2rg x 4cg with NT=4 -> only
// 256/512 output cols were computed per layer (cols 256..511 kept stale E0).
// Now NT=8: 8 waves = 2 row-groups x 4 col-groups, each 64 rows x 128 cols
// -> exact 128x512 coverage. eF back to R7's JIT rotating prefetch (2 live)
// so regs fit: acc 128 AGPR + wF dbuf 64 + eF 16 + addr ~15 ~= 238 <= 256.
// Swizzled unpadded LDS kept (conflict canary: SQ_LDS_BANK_CONFLICT < 3e6).

typedef short  short8  __attribute__((ext_vector_type(8)));
typedef short  short4v __attribute__((ext_vector_type(4)));
typedef float  f32x4   __attribute__((ext_vector_type(4)));

__device__ inline unsigned short f2bf(float x) {
  unsigned u = __float_as_uint(x);
  unsigned r = (u + 0x7FFFu + ((u >> 16) & 1u)) >> 16;  // RNE
  return (unsigned short)r;
}

// Swizzled LDS elem index. row = logical row, e = elem offset in row
// (0..511, 4-aligned). 16B chunk index (e>>3) is XORed with row&7.
__device__ inline int lds_e(int row, int e) {
  return row * 512 + ((((e >> 3) ^ (row & 7)) << 3) | (e & 7));
}

__device__ __host__ inline int wtile_off(int c, int k) {
  return ((c >> 4) * 16 + (k >> 5)) * 512 + (c & 15) * 32 + (k & 31);
}

template <int MT, int NT>
__device__ inline void zero_acc(f32x4 (&acc)[MT][NT]) {
#pragma unroll
  for (int mt = 0; mt < MT; ++mt)
#pragma unroll
    for (int nt = 0; nt < NT; ++nt) {
      f32x4 z = {0.f, 0.f, 0.f, 0.f};
      acc[mt][nt] = z;
    }
}

// acc[mt][nt] (+)= W-tile x E-tile.  W as MFMA A-operand (m = out-col),
// E as B-operand (n = edge-row).  Lane holds 4 consecutive out-cols
// (kg*4+r) at edge-row (mt*16 + (lane&15)).
// E: swizzled LDS; caller passes base pre-offset to the wave's row base
// (must be a multiple of 8 so row&7 == mrow&7).
// W: tiled layout (1KB fragment per (col_tile, kstep)).
// wF register double-buffered across ks; eF JIT rotating prefetch (2 live).
template <int MT, int NT>
__device__ inline void gemm_kloop(const short* E, const short* __restrict__ W,
                                  int lane, int nbase, f32x4 (&acc)[MT][NT]) {
  const int mrow = lane & 15, kg = lane >> 4, xorv = mrow & 7;
  const short* El = E + mrow * 512;
  const short* Wl = W + (nbase >> 4) * 8192 + mrow * 32 + kg * 8;
  short8 wF[2][NT];
#pragma unroll
  for (int nt = 0; nt < NT; ++nt) wF[0][nt] = *(const short8*)(Wl + nt * 8192);
#pragma unroll
  for (int ks = 0; ks < 16; ++ks) {
    const int cur = ks & 1, nxt = cur ^ 1;
    if (ks < 15) {
      const int k1 = (ks + 1) * 512;
#pragma unroll
      for (int nt = 0; nt < NT; ++nt)
        wF[nxt][nt] = *(const short8*)(Wl + nt * 8192 + k1);
    }
    const int ch = ((ks * 4 + kg) ^ xorv) << 3;
    short8 e0 = *(const short8*)(El + ch);
#pragma unroll
    for (int mt = 0; mt < MT; ++mt) {
      const short8 ecur = e0;
      if (mt < MT - 1) e0 = *(const short8*)(El + (mt + 1) * 8192 + ch);
#pragma unroll
      for (int nt = 0; nt < NT; ++nt)
        acc[mt][nt] = __builtin_amdgcn_mfma_f32_16x16x32_bf16(
            wF[cur][nt], ecur, acc[mt][nt], 0, 0, 0);
    }
  }
}

// relu(acc + bias[outcol]) -> bf16 -> swizzled LDS, 8B vector writes.
// E base pre-offset to wave row base (multiple of 8).
template <int MT, int NT>
__device__ inline void store_relu_lds(short* E, const float* __restrict__ bias,
                                      int lane, int nbase, f32x4 (&acc)[MT][NT]) {
  const int mrow = lane & 15, kg = lane >> 4;
#pragma unroll
  for (int nt = 0; nt < NT; ++nt) {
    const int oc = nbase + nt * 16 + kg * 4;
    const float4 bs = *(const float4*)(bias + oc);
#pragma unroll
    for (int mt = 0; mt < MT; ++mt) {
      const int row = mt * 16 + mrow;
      short4v s;
      s.x = (short)f2bf(fmaxf(acc[mt][nt][0] + bs.x, 0.f));
      s.y = (short)f2bf(fmaxf(acc[mt][nt][1] + bs.y, 0.f));
      s.z = (short)f2bf(fmaxf(acc[mt][nt][2] + bs.z, 0.f));
      s.w = (short)f2bf(fmaxf(acc[mt][nt][3] + bs.w, 0.f));
      *(short4v*)&E[lds_e(row, oc)] = s;
    }
  }
}

// ---------------- prep: fp32 -> bf16 + tiled relayout ----------------
__global__ void prep_kernel(const float* __restrict__ Wa, const float* __restrict__ Wb,
                            const float* __restrict__ Wca, const float* __restrict__ Wcb,
                            const float* __restrict__ Wcc, const float* __restrict__ Wout,
                            short* __restrict__ outS) {
  const int tid = blockIdx.x * blockDim.x + threadIdx.x;
  const int stride = gridDim.x * blockDim.x;
  const int M = 262144;
  for (int i = tid; i < 6 * M + 1024; i += stride) {
    float x;
    int dst;
    if (i < M) {                       // WaB tiled
      const int c = i >> 9, k = i & 511;
      x = Wa[i];
      dst = wtile_off(c, k);
    } else if (i < 2 * M) {            // WbB tiled
      const int t = i - M, c = t >> 9, k = t & 511;
      x = Wb[t];
      dst = M + wtile_off(c, k);
    } else if (i < 3 * M) {            // Wuv: u-half, tiled cols 0..511
      const int t = i - 2 * M, c = t >> 9, k = t & 511;
      x = Wca[c * 1024 + k];
      dst = 2 * M + wtile_off(c, k);
    } else if (i < 4 * M) {            // Wuv: v-half, tiled cols 512..1023
      const int t = i - 3 * M, c = t >> 9, k = t & 511;
      x = Wca[c * 1024 + 512 + k];
      dst = 2 * M + wtile_off(512 + c, k);
    } else if (i < 5 * M) {            // WcbB tiled
      const int t = i - 4 * M, c = t >> 9, k = t & 511;
      x = Wcb[t];
      dst = 4 * M + wtile_off(c, k);
    } else if (i < 6 * M) {            // WccB tiled
      const int t = i - 5 * M, c = t >> 9, k = t & 511;
      x = Wcc[t];
      dst = 5 * M + wtile_off(c, k);
    } else {                           // Wout plain row-major
      x = Wout[i - 6 * M];
      dst = i;
    }
    outS[dst] = (short)f2bf(x);
  }
}

// ---------------- node stage: 3 per-layer tiled kernels (64 rows x 64 cols) ---
// MODE 1: X=bv fp32, out = relu(X@Wa^T + xy-term + ba + bxy) -> bf16
// MODE 2: X=f1 bf16, out = relu(X@Wb^T + bb) -> bf16
// MODE 3: X=f2 bf16, out = X@Wuv^T (1024 cols) -> fp32 u (cols<512) / v (>=512)
template <int MODE>
__global__ __launch_bounds__(256, 4) void node_layer(
    const void* __restrict__ Xin, const short* __restrict__ W,
    const float* __restrict__ bias, const float* __restrict__ xy,
    const float* __restrict__ Wxy, const float* __restrict__ bxy,
    void* __restrict__ Yout, float* __restrict__ vout, int colTiles) {
  __shared__ short X[64 * 512];
  __shared__ float xyl[128];
  const int tid = threadIdx.x, lane = tid & 63, wave = tid >> 6;
  const int rt = blockIdx.x / colTiles, ct = blockIdx.x % colTiles;
  const int row0 = rt * 64, c0 = ct * 64;

  if (MODE == 1) {
    const float* bv = (const float*)Xin;
    const int hc = (tid & 127) * 4, m0 = tid >> 7;
    for (int m = m0; m < 64; m += 2) {
      const float4 t = *(const float4*)(bv + (row0 + m) * 512 + hc);
      short4v s;
      s.x = (short)f2bf(t.x); s.y = (short)f2bf(t.y);
      s.z = (short)f2bf(t.z); s.w = (short)f2bf(t.w);
      *(short4v*)&X[lds_e(m, hc)] = s;
    }
    if (tid < 128) xyl[tid] = xy[row0 * 2 + tid];
  } else {
    const short* xb = (const short*)Xin;
    const int hc = (tid & 63) * 8, m0 = tid >> 6;
    for (int m = m0; m < 64; m += 4)
      *(short8*)&X[lds_e(m, hc)] = *(const short8*)(xb + (row0 + m) * 512 + hc);
  }
  __syncthreads();

  const int nbase = c0 + wave * 16;
  f32x4 acc[4][1];
  zero_acc<4, 1>(acc);
  gemm_kloop<4, 1>(X, W, lane, nbase, acc);

  const int mrow = lane & 15, kg = lane >> 4;
  const int oc = nbase + kg * 4;
  if (MODE == 3) {
    float* u = (float*)Yout;
#pragma unroll
    for (int mt = 0; mt < 4; ++mt) {
      const int row = row0 + mt * 16 + mrow;
      if (oc < 512) *(f32x4*)&u[row * 512 + oc] = acc[mt][0];     // block-uniform branch
      else          *(f32x4*)&vout[row * 512 + oc - 512] = acc[mt][0];
    }
  } else {
    short* Y = (short*)Yout;
    const float4 bs = *(const float4*)(bias + oc);
    float b2[4] = {0.f, 0.f, 0.f, 0.f}, w0[4], w1[4];
    if (MODE == 1) {
      const float4 t = *(const float4*)(bxy + oc);
      b2[0] = t.x; b2[1] = t.y; b2[2] = t.z; b2[3] = t.w;
#pragma unroll
      for (int r = 0; r < 4; ++r) { w0[r] = Wxy[(oc + r) * 2]; w1[r] = Wxy[(oc + r) * 2 + 1]; }
    }
#pragma unroll
    for (int mt = 0; mt < 4; ++mt) {
      const int row = mt * 16 + mrow;
      short4v s;
#pragma unroll
      for (int r = 0; r < 4; ++r) {
        float xv = acc[mt][0][r] + ((const float*)&bs)[r];
        if (MODE == 1) xv += b2[r] + xyl[row * 2] * w0[r] + xyl[row * 2 + 1] * w1[r];
        ((short*)&s)[r] = (short)f2bf(fmaxf(xv, 0.f));
      }
      *(short4v*)&Y[(row0 + row) * 512 + oc] = s;
    }
  }
}

// ---------------- edge stage: fused E0 -> E1 -> E2 -> out ----------------
// 128-row tiles (2 i x 64 j): LDS 139,264 B -> 1 block/CU, 8 waves as
// 2 row-groups x 4 col-groups; each wave 64 rows (MT=4) x 128 cols (NT=8)
// -> full 128x512 layer coverage.  1152 blocks = 4.5 rounds of 256 CUs.
__global__ __launch_bounds__(512, 2) void edge_kernel(
    const float* __restrict__ u, const float* __restrict__ v,
    const short* __restrict__ Wcb, const short* __restrict__ Wcc,
    const short* __restrict__ Wout,
    const float* __restrict__ bca, const float* __restrict__ bcb,
    const float* __restrict__ bcc, const float* __restrict__ bout,
    float* __restrict__ out) {
  __shared__ short A[128 * 512];       // 131,072 B
  __shared__ float red[128 * 2 * 8];   //   8,192 B
  const int tid = threadIdx.x, lane = tid & 63, wave = tid >> 6;
  const int blk = blockIdx.x;
  const int b = blk / 288, rem = blk % 288, ip = rem / 3, jt = rem % 3;
  const float* urow0 = u + (b * 192 + jt * 64) * 512;  // row m: j = jt*64 + (m&63)
  const float* vrow0 = v + (b * 192 + ip * 2) * 512;   // row m: i = ip*2 + (m>>6)

  {  // Phase 0: E0 = relu(u[j] + v[i] + b_ca) -> bf16 swizzled LDS
    const int t = tid & 127, hc = t * 4, m0 = tid >> 7;
    const float4 v0 = *(const float4*)(vrow0 + hc);
    const float4 v1 = *(const float4*)(vrow0 + 512 + hc);
    const float4 bb = *(const float4*)(bca + hc);
#pragma unroll 4
    for (int m = m0; m < 128; m += 4) {
      const float4 vv = (m >> 6) ? v1 : v0;
      const float4 uu = *(const float4*)(urow0 + (m & 63) * 512 + hc);
      short4v s;
      s.x = (short)f2bf(fmaxf(uu.x + vv.x + bb.x, 0.f));
      s.y = (short)f2bf(fmaxf(uu.y + vv.y + bb.y, 0.f));
      s.z = (short)f2bf(fmaxf(uu.z + vv.z + bb.z, 0.f));
      s.w = (short)f2bf(fmaxf(uu.w + vv.w + bb.w, 0.f));
      *(short4v*)&A[lds_e(m, hc)] = s;
    }
  }
  __syncthreads();

  const int rg = wave >> 2, cg = wave & 3;
  const int nbase = cg * 128;
  short* Aw = A + (rg * 64) * 512;     // wave's 64-row half (row base mult of 8)
  f32x4 acc[4][8];

  // layer cb
  zero_acc<4, 8>(acc);
  gemm_kloop<4, 8>(Aw, Wcb, lane, nbase, acc);
  __syncthreads();                 // all waves done reading E0
  store_relu_lds<4, 8>(Aw, bcb, lane, nbase, acc);
  __syncthreads();

  // layer cc
  zero_acc<4, 8>(acc);
  gemm_kloop<4, 8>(Aw, Wcc, lane, nbase, acc);
  __syncthreads();
  store_relu_lds<4, 8>(Aw, bcc, lane, nbase, acc);
  __syncthreads();

  // final: out = E2 @ Wout^T + bout.  k-split across 8 waves, n padded 2->16.
  f32x4 oacc[8];
#pragma unroll
  for (int mt = 0; mt < 8; ++mt) { f32x4 z = {0.f, 0.f, 0.f, 0.f}; oacc[mt] = z; }
  const int n2 = lane & 15, kg2 = lane >> 4;
#pragma unroll
  for (int kk = 0; kk < 2; ++kk) {
    const int e = wave * 64 + kk * 32 + kg2 * 8;
    short8 bf = {0, 0, 0, 0, 0, 0, 0, 0};
    if (n2 < 2) bf = *(const short8*)(Wout + n2 * 512 + e);
#pragma unroll
    for (int mt = 0; mt < 8; ++mt) {
      const short8 af = *(const short8*)&A[lds_e(mt * 16 + n2, e)];
      oacc[mt] = __builtin_amdgcn_mfma_f32_16x16x32_bf16(af, bf, oacc[mt], 0, 0, 0);
    }
  }
  if (n2 < 2) {
#pragma unroll
    for (int mt = 0; mt < 8; ++mt)
#pragma unroll
      for (int r = 0; r < 4; ++r) {
        const int row = mt * 16 + kg2 * 4 + r;
        red[(row * 2 + n2) * 8 + wave] = oacc[mt][r];
      }
  }
  __syncthreads();
  if (tid < 256) {
    const int row = tid >> 1, o = tid & 1;
    float s = bout[o];
#pragma unroll
    for (int w = 0; w < 8; ++w) s += red[(row * 2 + o) * 8 + w];
    const int i = ip * 2 + (row >> 6), j = jt * 64 + (row & 63);
    out[((b * 192 + i) * 192 + j) * 2 + o] = s;
  }
}

extern "C" void kernel_launch(void* const* d_in, const int* in_sizes, int n_in,
                              void* d_out, int out_size, void* d_ws, size_t ws_size,
                              hipStream_t stream) {
  const float* bv   = (const float*)d_in[0];
  const float* xy   = (const float*)d_in[1];
  const float* Wxy  = (const float*)d_in[2];
  const float* bxy  = (const float*)d_in[3];
  const float* Wa   = (const float*)d_in[4];
  const float* ba   = (const float*)d_in[5];
  const float* Wb   = (const float*)d_in[6];
  const float* bb   = (const float*)d_in[7];
  const float* Wca  = (const float*)d_in[8];
  const float* bca  = (const float*)d_in[9];
  const float* Wcb  = (const float*)d_in[10];
  const float* bcb  = (const float*)d_in[11];
  const float* Wcc  = (const float*)d_in[12];
  const float* bcc  = (const float*)d_in[13];
  const float* Wout = (const float*)d_in[14];
  const float* bout = (const float*)d_in[15];
  float* out = (float*)d_out;

  // ws layout (bytes): [0, 3,147,776) bf16 weights (tiled layout);
  // f1 bf16 @3,147,776 (aliased by u fp32, f1 dead before L3 writes u);
  // f2 bf16 @4,720,640; v fp32 @5,507,072; end 7,079,936.
  short* S = (short*)d_ws;
  char* base = (char*)d_ws;
  short* WaB   = S;
  short* WbB   = S + 262144;
  short* WuvB  = S + 524288;    // tiled, 1024 cols: ct 0-31 = W1 (u), 32-63 = W2 (v)
  short* WcbB  = S + 1048576;
  short* WccB  = S + 1310720;
  short* WoutB = S + 1572864;
  short* f1 = (short*)(base + 3147776);
  float* u  = (float*)(base + 3147776);
  short* f2 = (short*)(base + 4720640);
  float* v  = (float*)(base + 5507072);

  prep_kernel<<<512, 256, 0, stream>>>(Wa, Wb, Wca, Wcb, Wcc, Wout, S);
  node_layer<1><<<96, 256, 0, stream>>>(bv, WaB, ba, xy, Wxy, bxy, f1, nullptr, 8);
  node_layer<2><<<96, 256, 0, stream>>>(f1, WbB, bb, nullptr, nullptr, nullptr, f2, nullptr, 8);
  node_layer<3><<<192, 256, 0, stream>>>(f2, WuvB, nullptr, nullptr, nullptr, nullptr, u, v, 16);
  edge_kernel<<<1152, 512, 0, stream>>>(u, v, WcbB, WccB, WoutB, bca, bcb, bcc, bout, out);
}

// Round 10
// 335.285 us; speedup vs baseline: 1.0555x; 1.0555x over previous
//
#include <hip/hip_runtime.h>

// BrickVectorEdgeModel on MI355X (gfx950).
// R10: R7 exact structure (144-row tiles, MT=9/NT=4, wF dbuf + eF rotating,
// ~200 regs -- the proven no-spill budget) + XOR-swizzled unpadded LDS
// (chunk ^= row&7: every ds_read_b128 phase covers all 32 banks 2-way) +
// dst-major vectorized prep (1KB/wave sequential writes).
// Canaries: SQ_LDS_BANK_CONFLICT < 2e6, WRITE_SIZE ~3.8MB (no spills).

typedef short  short8  __attribute__((ext_vector_type(8)));
typedef short  short4v __attribute__((ext_vector_type(4)));
typedef float  f32x4   __attribute__((ext_vector_type(4)));

__device__ inline unsigned short f2bf(float x) {
  unsigned u = __float_as_uint(x);
  unsigned r = (u + 0x7FFFu + ((u >> 16) & 1u)) >> 16;  // RNE
  return (unsigned short)r;
}

// Swizzled LDS elem index. row = logical row, e = elem offset in row
// (0..511, 4-aligned). 16B chunk index (e>>3) XORed with row&7.
__device__ inline int lds_e(int row, int e) {
  return row * 512 + ((((e >> 3) ^ (row & 7)) << 3) | (e & 7));
}

template <int MT, int NT>
__device__ inline void zero_acc(f32x4 (&acc)[MT][NT]) {
#pragma unroll
  for (int mt = 0; mt < MT; ++mt)
#pragma unroll
    for (int nt = 0; nt < NT; ++nt) {
      f32x4 z = {0.f, 0.f, 0.f, 0.f};
      acc[mt][nt] = z;
    }
}

// acc[mt][nt] (+)= W-tile x E-tile.  W as MFMA A-operand (m = out-col),
// E as B-operand (n = edge-row).  Lane holds 4 consecutive out-cols
// (kg*4+r) at edge-row (mt*16 + (lane&15)).
// E: swizzled LDS (row base of caller must be multiple of 8; here 0).
// W: tiled layout, contiguous 1KB fragment per (col_tile, kstep).
// wF register double-buffered across ks; eF JIT rotating prefetch (2 live).
template <int MT, int NT>
__device__ inline void gemm_kloop(const short* E, const short* __restrict__ W,
                                  int lane, int nbase, f32x4 (&acc)[MT][NT]) {
  const int mrow = lane & 15, kg = lane >> 4, xorv = mrow & 7;
  const short* El = E + mrow * 512;
  const short* Wl = W + (nbase >> 4) * 8192 + mrow * 32 + kg * 8;
  short8 wF[2][NT];
#pragma unroll
  for (int nt = 0; nt < NT; ++nt) wF[0][nt] = *(const short8*)(Wl + nt * 8192);
#pragma unroll
  for (int ks = 0; ks < 16; ++ks) {
    const int cur = ks & 1, nxt = cur ^ 1;
    if (ks < 15) {
      const int k1 = (ks + 1) * 512;
#pragma unroll
      for (int nt = 0; nt < NT; ++nt)
        wF[nxt][nt] = *(const short8*)(Wl + nt * 8192 + k1);
    }
    const int ch = ((ks * 4 + kg) ^ xorv) << 3;
    short8 e0 = *(const short8*)(El + ch);
#pragma unroll
    for (int mt = 0; mt < MT; ++mt) {
      const short8 ecur = e0;
      if (mt < MT - 1) e0 = *(const short8*)(El + (mt + 1) * 8192 + ch);
#pragma unroll
      for (int nt = 0; nt < NT; ++nt)
        acc[mt][nt] = __builtin_amdgcn_mfma_f32_16x16x32_bf16(
            wF[cur][nt], ecur, acc[mt][nt], 0, 0, 0);
    }
  }
}

// relu(acc + bias[outcol]) -> bf16 -> swizzled LDS, 8B vector writes.
template <int MT, int NT>
__device__ inline void store_relu_lds(short* E, const float* __restrict__ bias,
                                      int lane, int nbase, f32x4 (&acc)[MT][NT]) {
  const int mrow = lane & 15, kg = lane >> 4;
#pragma unroll
  for (int nt = 0; nt < NT; ++nt) {
    const int oc = nbase + nt * 16 + kg * 4;
    const float4 bs = *(const float4*)(bias + oc);
#pragma unroll
    for (int mt = 0; mt < MT; ++mt) {
      const int row = mt * 16 + mrow;
      short4v s;
      s.x = (short)f2bf(fmaxf(acc[mt][nt][0] + bs.x, 0.f));
      s.y = (short)f2bf(fmaxf(acc[mt][nt][1] + bs.y, 0.f));
      s.z = (short)f2bf(fmaxf(acc[mt][nt][2] + bs.z, 0.f));
      s.w = (short)f2bf(fmaxf(acc[mt][nt][3] + bs.w, 0.f));
      *(short4v*)&E[lds_e(row, oc)] = s;
    }
  }
}

// ---------------- prep: fp32 -> bf16 + tiled relayout, dst-major ----------
// Tiled W layout (per 512-col weight): dst = tile*512 + (c&15)*32 + (k&31),
// tile = (c>>4)*16 + (k>>5). dst-major: each thread fills 8 consecutive dst
// elems (same c, 8 consecutive k) -> wave writes 1KB sequential.
__global__ void prep_kernel(const float* __restrict__ Wa, const float* __restrict__ Wb,
                            const float* __restrict__ Wca, const float* __restrict__ Wcb,
                            const float* __restrict__ Wcc, const float* __restrict__ Wout,
                            short* __restrict__ outS) {
  const int tid = blockIdx.x * blockDim.x + threadIdx.x;
  const int stride = gridDim.x * blockDim.x;
  const int M = 262144;
  const int NV = (6 * M + 1024) / 8;
  for (int idx = tid; idx < NV; idx += stride) {
    const int d0 = idx * 8;
    const float* src;
    if (d0 >= 6 * M) {                    // Wout plain copy
      src = Wout + (d0 - 6 * M);
    } else {
      const int r = d0 / M;               // region 0..5 (r2&r3 = Wuv 2M region)
      if (r == 2 || r == 3) {
        const int t = d0 - 2 * M;         // 0..2M
        const int tile = t >> 9, l = t & 511;
        const int c = (tile >> 4) * 16 + (l >> 5);     // 0..1023
        const int k = (tile & 15) * 32 + (l & 31);
        src = (c < 512) ? (Wca + c * 1024 + k) : (Wca + (c - 512) * 1024 + 512 + k);
      } else {
        const int t = d0 - r * M;
        const int tile = t >> 9, l = t & 511;
        const int c = (tile >> 4) * 16 + (l >> 5);
        const int k = (tile & 15) * 32 + (l & 31);
        const float* base = (r == 0) ? Wa : (r == 1) ? Wb : (r == 4) ? Wcb : Wcc;
        src = base + c * 512 + k;
      }
    }
    const float4 a = *(const float4*)src;
    const float4 b = *(const float4*)(src + 4);
    short8 s;
    s[0] = (short)f2bf(a.x); s[1] = (short)f2bf(a.y);
    s[2] = (short)f2bf(a.z); s[3] = (short)f2bf(a.w);
    s[4] = (short)f2bf(b.x); s[5] = (short)f2bf(b.y);
    s[6] = (short)f2bf(b.z); s[7] = (short)f2bf(b.w);
    *(short8*)(outS + d0) = s;
  }
}

// ---------------- node stage: 3 per-layer tiled kernels (64 rows x 64 cols) ---
// MODE 1: X=bv fp32, out = relu(X@Wa^T + xy-term + ba + bxy) -> bf16
// MODE 2: X=f1 bf16, out = relu(X@Wb^T + bb) -> bf16
// MODE 3: X=f2 bf16, out = X@Wuv^T (1024 cols) -> fp32 u (cols<512) / v (>=512)
template <int MODE>
__global__ __launch_bounds__(256, 4) void node_layer(
    const void* __restrict__ Xin, const short* __restrict__ W,
    const float* __restrict__ bias, const float* __restrict__ xy,
    const float* __restrict__ Wxy, const float* __restrict__ bxy,
    void* __restrict__ Yout, float* __restrict__ vout, int colTiles) {
  __shared__ short X[64 * 512];
  __shared__ float xyl[128];
  const int tid = threadIdx.x, lane = tid & 63, wave = tid >> 6;
  const int rt = blockIdx.x / colTiles, ct = blockIdx.x % colTiles;
  const int row0 = rt * 64, c0 = ct * 64;

  if (MODE == 1) {
    const float* bv = (const float*)Xin;
    const int hc = (tid & 127) * 4, m0 = tid >> 7;
    for (int m = m0; m < 64; m += 2) {
      const float4 t = *(const float4*)(bv + (row0 + m) * 512 + hc);
      short4v s;
      s.x = (short)f2bf(t.x); s.y = (short)f2bf(t.y);
      s.z = (short)f2bf(t.z); s.w = (short)f2bf(t.w);
      *(short4v*)&X[lds_e(m, hc)] = s;
    }
    if (tid < 128) xyl[tid] = xy[row0 * 2 + tid];
  } else {
    const short* xb = (const short*)Xin;
    const int hc = (tid & 63) * 8, m0 = tid >> 6;
    for (int m = m0; m < 64; m += 4)
      *(short8*)&X[lds_e(m, hc)] = *(const short8*)(xb + (row0 + m) * 512 + hc);
  }
  __syncthreads();

  const int nbase = c0 + wave * 16;
  f32x4 acc[4][1];
  zero_acc<4, 1>(acc);
  gemm_kloop<4, 1>(X, W, lane, nbase, acc);

  const int mrow = lane & 15, kg = lane >> 4;
  const int oc = nbase + kg * 4;
  if (MODE == 3) {
    float* u = (float*)Yout;
#pragma unroll
    for (int mt = 0; mt < 4; ++mt) {
      const int row = row0 + mt * 16 + mrow;
      if (oc < 512) *(f32x4*)&u[row * 512 + oc] = acc[mt][0];     // block-uniform branch
      else          *(f32x4*)&vout[row * 512 + oc - 512] = acc[mt][0];
    }
  } else {
    short* Y = (short*)Yout;
    const float4 bs = *(const float4*)(bias + oc);
    float b2[4] = {0.f, 0.f, 0.f, 0.f}, w0[4], w1[4];
    if (MODE == 1) {
      const float4 t = *(const float4*)(bxy + oc);
      b2[0] = t.x; b2[1] = t.y; b2[2] = t.z; b2[3] = t.w;
#pragma unroll
      for (int r = 0; r < 4; ++r) { w0[r] = Wxy[(oc + r) * 2]; w1[r] = Wxy[(oc + r) * 2 + 1]; }
    }
#pragma unroll
    for (int mt = 0; mt < 4; ++mt) {
      const int row = mt * 16 + mrow;
      short4v s;
#pragma unroll
      for (int r = 0; r < 4; ++r) {
        float xv = acc[mt][0][r] + ((const float*)&bs)[r];
        if (MODE == 1) xv += b2[r] + xyl[row * 2] * w0[r] + xyl[row * 2 + 1] * w1[r];
        ((short*)&s)[r] = (short)f2bf(fmaxf(xv, 0.f));
      }
      *(short4v*)&Y[(row0 + row) * 512 + oc] = s;
    }
  }
}

// ---------------- edge stage: fused E0 -> E1 -> E2 -> out ----------------
// 144-row tiles (3 i x 48 j): swizzled LDS 147,456 B + red 9,216 = 156,672 B
// -> 1 block/CU, 8 waves.  1024 blocks = exactly 4 rounds of 256 CUs.
__global__ __launch_bounds__(512, 2) void edge_kernel(
    const float* __restrict__ u, const float* __restrict__ v,
    const short* __restrict__ Wcb, const short* __restrict__ Wcc,
    const short* __restrict__ Wout,
    const float* __restrict__ bca, const float* __restrict__ bcb,
    const float* __restrict__ bcc, const float* __restrict__ bout,
    float* __restrict__ out) {
  __shared__ short A[144 * 512];       // 147,456 B
  __shared__ float red[144 * 2 * 8];   //   9,216 B
  const int tid = threadIdx.x, lane = tid & 63, wave = tid >> 6;
  const int blk = blockIdx.x;
  const int b = blk >> 8, rem = blk & 255, ip = rem >> 2, jt = rem & 3;
  const float* urow0 = u + (b * 192 + jt * 48) * 512;        // row m: j = jt*48 + m%48
  const float* vrow0 = v + (b * 192 + ip * 3) * 512;         // row m: i = ip*3 + m/48

  {  // Phase 0: E0 = relu(u[j] + v[i] + b_ca) -> bf16 swizzled LDS
    const int hc = (tid & 127) * 4, m0 = tid >> 7;
    const float4 v0 = *(const float4*)(vrow0 + hc);
    const float4 v1 = *(const float4*)(vrow0 + 512 + hc);
    const float4 v2 = *(const float4*)(vrow0 + 1024 + hc);
    const float4 bb = *(const float4*)(bca + hc);
#pragma unroll 4
    for (int m = m0; m < 144; m += 4) {
      const int ii = (m >= 96) ? 2 : (m >= 48 ? 1 : 0);
      const int jj = m - ii * 48;
      const float4 vv = (ii == 0) ? v0 : (ii == 1) ? v1 : v2;
      const float4 uu = *(const float4*)(urow0 + jj * 512 + hc);
      short4v s;
      s.x = (short)f2bf(fmaxf(uu.x + vv.x + bb.x, 0.f));
      s.y = (short)f2bf(fmaxf(uu.y + vv.y + bb.y, 0.f));
      s.z = (short)f2bf(fmaxf(uu.z + vv.z + bb.z, 0.f));
      s.w = (short)f2bf(fmaxf(uu.w + vv.w + bb.w, 0.f));
      *(short4v*)&A[lds_e(m, hc)] = s;
    }
  }
  __syncthreads();

  const int nbase = wave * 64;
  f32x4 acc[9][4];

  // layer cb
  zero_acc<9, 4>(acc);
  gemm_kloop<9, 4>(A, Wcb, lane, nbase, acc);
  __syncthreads();                 // all waves done reading E0
  store_relu_lds<9, 4>(A, bcb, lane, nbase, acc);
  __syncthreads();

  // layer cc
  zero_acc<9, 4>(acc);
  gemm_kloop<9, 4>(A, Wcc, lane, nbase, acc);
  __syncthreads();
  store_relu_lds<9, 4>(A, bcc, lane, nbase, acc);
  __syncthreads();

  // final: out = E2 @ Wout^T + bout.  k-split across 8 waves, n padded 2->16.
  f32x4 oacc[9];
#pragma unroll
  for (int mt = 0; mt < 9; ++mt) { f32x4 z = {0.f, 0.f, 0.f, 0.f}; oacc[mt] = z; }
  const int n2 = lane & 15, kg2 = lane >> 4;
#pragma unroll
  for (int kk = 0; kk < 2; ++kk) {
    const int e = wave * 64 + kk * 32 + kg2 * 8;
    short8 bf = {0, 0, 0, 0, 0, 0, 0, 0};
    if (n2 < 2) bf = *(const short8*)(Wout + n2 * 512 + e);
#pragma unroll
    for (int mt = 0; mt < 9; ++mt) {
      const short8 af = *(const short8*)&A[lds_e(mt * 16 + n2, e)];
      oacc[mt] = __builtin_amdgcn_mfma_f32_16x16x32_bf16(af, bf, oacc[mt], 0, 0, 0);
    }
  }
  if (n2 < 2) {
#pragma unroll
    for (int mt = 0; mt < 9; ++mt)
#pragma unroll
      for (int r = 0; r < 4; ++r) {
        const int row = mt * 16 + kg2 * 4 + r;
        red[(row * 2 + n2) * 8 + wave] = oacc[mt][r];
      }
  }
  __syncthreads();
  if (tid < 288) {
    const int row = tid >> 1, o = tid & 1;
    float s = bout[o];
#pragma unroll
    for (int w = 0; w < 8; ++w) s += red[(row * 2 + o) * 8 + w];
    const int ii = (row >= 96) ? 2 : (row >= 48 ? 1 : 0);
    const int jj = row - ii * 48;
    out[((b * 192 + ip * 3 + ii) * 192 + jt * 48 + jj) * 2 + o] = s;
  }
}

extern "C" void kernel_launch(void* const* d_in, const int* in_sizes, int n_in,
                              void* d_out, int out_size, void* d_ws, size_t ws_size,
                              hipStream_t stream) {
  const float* bv   = (const float*)d_in[0];
  const float* xy   = (const float*)d_in[1];
  const float* Wxy  = (const float*)d_in[2];
  const float* bxy  = (const float*)d_in[3];
  const float* Wa   = (const float*)d_in[4];
  const float* ba   = (const float*)d_in[5];
  const float* Wb   = (const float*)d_in[6];
  const float* bb   = (const float*)d_in[7];
  const float* Wca  = (const float*)d_in[8];
  const float* bca  = (const float*)d_in[9];
  const float* Wcb  = (const float*)d_in[10];
  const float* bcb  = (const float*)d_in[11];
  const float* Wcc  = (const float*)d_in[12];
  const float* bcc  = (const float*)d_in[13];
  const float* Wout = (const float*)d_in[14];
  const float* bout = (const float*)d_in[15];
  float* out = (float*)d_out;

  // ws layout (bytes): [0, 3,147,776) bf16 weights (tiled layout);
  // f1 bf16 @3,147,776 (aliased by u fp32, f1 dead before L3 writes u);
  // f2 bf16 @4,720,640; v fp32 @5,507,072; end 7,079,936.
  short* S = (short*)d_ws;
  char* base = (char*)d_ws;
  short* WaB   = S;
  short* WbB   = S + 262144;
  short* WuvB  = S + 524288;    // tiled, 1024 cols: ct 0-31 = W1 (u), 32-63 = W2 (v)
  short* WcbB  = S + 1048576;
  short* WccB  = S + 1310720;
  short* WoutB = S + 1572864;
  short* f1 = (short*)(base + 3147776);
  float* u  = (float*)(base + 3147776);
  short* f2 = (short*)(base + 4720640);
  float* v  = (float*)(base + 5507072);

  prep_kernel<<<512, 256, 0, stream>>>(Wa, Wb, Wca, Wcb, Wcc, Wout, S);
  node_layer<1><<<96, 256, 0, stream>>>(bv, WaB, ba, xy, Wxy, bxy, f1, nullptr, 8);
  node_layer<2><<<96, 256, 0, stream>>>(f1, WbB, bb, nullptr, nullptr, nullptr, f2, nullptr, 8);
  node_layer<3><<<192, 256, 0, stream>>>(f2, WuvB, nullptr, nullptr, nullptr, nullptr, u, v, 16);
  edge_kernel<<<1024, 512, 0, stream>>>(u, v, WcbB, WccB, WoutB, bca, bcb, bcc, bout, out);
}